// Round 3
// baseline (295.604 us; speedup 1.0000x reference)
//
#include <hip/hip_runtime.h>
#include <hip/hip_bf16.h>

#define H  32
#define W  32
#define CI 32
#define CO 64
#define NB 8
#define NOUT 32

// d_out float offsets: [w_u | b_u | w_l | b_l]
#define WU_OFF 0
#define BU_OFF (NB * H * W * CI * NOUT)          // 8388608
#define WL_OFF (BU_OFF + NB * NOUT)              // 8388864
#define BL_OFF (WL_OFF + NB * H * W * CI * NOUT) // 16777472

// d_ws layout: [0, 36864) bf16 A-fragments; [36864, 36864+131072) double bias partials
#define KF_UINT4 2304
#define BP_OFF_BYTES (KF_UINT4 * 16)             // 36864, 8-aligned

typedef __bf16 bf16x8 __attribute__((ext_vector_type(8)));
typedef float  f32x4  __attribute__((ext_vector_type(4)));

// round-half-up fp32 -> bf16, packed pair (lo in bits 0..15)
__device__ __forceinline__ unsigned int pack_bf16(float lo, float hi) {
    unsigned int ulo = __float_as_uint(lo) + 0x8000u;
    unsigned int uhi = __float_as_uint(hi) + 0x8000u;
    return (uhi & 0xffff0000u) | (ulo >> 16);
}

// Swizzle conv kernel K[3][3][32][64] fp32 -> bf16 A-fragments.
// frag[(tap*4 + c*2 + ih)][lane] = 8 bf16, lane holds A[m=ih*16+(lane&15)]
// [k=(lane>>4)*8+j], o = c*32 + k.  (HW-verified: conv output passed R1+R2.)
__global__ void prep_kernel(const float* __restrict__ K,
                            unsigned int* __restrict__ kws) {
    int g    = blockIdx.x * 256 + threadIdx.x;  // 0..2303
    int tap  = g >> 8;
    int r    = g & 255;
    int i    = r >> 3;
    int og   = r & 7;
    int c    = og >> 2;
    int quad = og & 3;
    int ih   = i >> 4;
    int lane = quad * 16 + (i & 15);
    int dst  = ((tap * 4 + c * 2 + ih) * 64 + lane) * 4;
    const float4* src = (const float4*)(K + (size_t)g * 8);
    float4 f0 = src[0];
    float4 f1 = src[1];
    kws[dst + 0] = pack_bf16(f0.x, f0.y);
    kws[dst + 1] = pack_bf16(f0.z, f0.w);
    kws[dst + 2] = pack_bf16(f1.x, f1.y);
    kws[dst + 3] = pack_bf16(f1.z, f1.w);
}

// One wave per (side, b, h, w): out tile [i=32][n=32] via 2x2 mfma 16x16x32 bf16.
// Conv ONLY — no bias logic (frozen: passed R1+R2).
__global__ __launch_bounds__(256, 4)
void conv_bwd_kernel(const float* __restrict__ wu,
                     const float* __restrict__ wl,
                     const uint4* __restrict__ kws,
                     float* __restrict__ out) {
    __shared__ uint4 kf[KF_UINT4];      // 36 KB A-fragments

    int t = threadIdx.x;
#pragma unroll
    for (int k = 0; k < 9; k++) kf[t + 256 * k] = kws[t + 256 * k];
    __syncthreads();

    int bx   = blockIdx.x;
    int side = bx >> 11;
    int rem  = bx & 2047;
    int b    = rem >> 8;
    int slot = rem & 255;
    int h    = slot >> 3;
    int wq   = slot & 7;
    int wave = t >> 6;
    int lane = t & 63;
    int w    = wq * 4 + wave;
    int n16  = lane & 15;
    int quad = lane >> 4;

    const float* in  = side ? wl : wu;
    const float* inb = in + (size_t)b * (H * W * CO * NOUT);

    f32x4 acc[2][2] = {};
    const bf16x8* kfp = (const bf16x8*)kf;

#pragma unroll
    for (int kh = 0; kh < 3; kh++) {
        int hi = h + 1 - kh;
        if (hi < 0 || hi >= H) continue;
#pragma unroll
        for (int kw = 0; kw < 3; kw++) {
            int wi = w + 1 - kw;
            if (wi < 0 || wi >= W) continue;
            int tap = kh * 3 + kw;
            const float* p = inb + (size_t)((hi * W + wi) * CO) * NOUT;
#pragma unroll
            for (int c = 0; c < 2; c++) {
                int ob = c * 32 + quad * 8;
                const float* p0 = p + ob * NOUT + n16;
                float v0[8], v1[8];
#pragma unroll
                for (int j = 0; j < 8; j++) {
                    v0[j] = p0[j * NOUT];        // (o=ob+j, n=n16)
                    v1[j] = p0[j * NOUT + 16];   // (o=ob+j, n=n16+16)
                }
                union { unsigned int u[4]; bf16x8 v; } b0, b1;
#pragma unroll
                for (int j = 0; j < 4; j++) {
                    b0.u[j] = pack_bf16(v0[2 * j], v0[2 * j + 1]);
                    b1.u[j] = pack_bf16(v1[2 * j], v1[2 * j + 1]);
                }
                bf16x8 a0 = kfp[(tap * 4 + c * 2 + 0) * 64 + lane];
                bf16x8 a1 = kfp[(tap * 4 + c * 2 + 1) * 64 + lane];
                acc[0][0] = __builtin_amdgcn_mfma_f32_16x16x32_bf16(a0, b0.v, acc[0][0], 0, 0, 0);
                acc[0][1] = __builtin_amdgcn_mfma_f32_16x16x32_bf16(a0, b1.v, acc[0][1], 0, 0, 0);
                acc[1][0] = __builtin_amdgcn_mfma_f32_16x16x32_bf16(a1, b0.v, acc[1][0], 0, 0, 0);
                acc[1][1] = __builtin_amdgcn_mfma_f32_16x16x32_bf16(a1, b1.v, acc[1][1], 0, 0, 0);
            }
        }
    }

    // epilogue: C/D layout col = lane&15, row = quad*4 + reg (HW-verified)
    float* wout = out + (side ? WL_OFF : WU_OFF)
                + (size_t)b * (H * W * CI * NOUT)
                + (size_t)((h * W + w) * CI) * NOUT;
#pragma unroll
    for (int ih = 0; ih < 2; ih++)
#pragma unroll
        for (int nh = 0; nh < 2; nh++)
#pragma unroll
            for (int r = 0; r < 4; r++) {
                int i = ih * 16 + quad * 4 + r;
                int n = nh * 16 + n16;
                wout[i * NOUT + n] = acc[ih][nh][r];
            }
}

// Dead-simple bias einsum, straight off the reference formula:
//   b_new[b,n] = b[b,n] + sum_f w[b,f,n] * bias[f & 63]
// Stage 1: one block per (side, b, h); fp64 accumulation (bit-deterministic).
__global__ __launch_bounds__(256)
void bias_part_kernel(const float* __restrict__ wu,
                      const float* __restrict__ wl,
                      const float* __restrict__ bias,
                      double* __restrict__ bpart) {
    __shared__ double sred[8][32];
    __shared__ float bias_s[CO];
    int t = threadIdx.x;
    if (t < CO) bias_s[t] = bias[t];
    __syncthreads();

    int blk  = blockIdx.x;       // 0..511
    int sb   = blk >> 5;         // side*8 + b
    int h    = blk & 31;
    int side = sb >> 3, b = sb & 7;
    const float* in = (side ? wl : wu)
                    + (size_t)b * (H * W * CO * NOUT)
                    + (size_t)h * (W * CO * NOUT);
    int lane = t & 31;           // n
    int g    = t >> 5;           // 0..7
    double acc = 0.0;
    for (int f = g; f < W * CO; f += 8) {
        float v = in[(size_t)f * NOUT + lane];   // coalesced 128 B per group
        acc += (double)v * (double)bias_s[f & 63];
    }
    sred[g][lane] = acc;
    __syncthreads();
    if (t < 32) {
        double s = 0.0;
#pragma unroll
        for (int g2 = 0; g2 < 8; g2++) s += sred[g2][t];
        bpart[(size_t)blk * 32 + t] = s;
    }
}

// Stage 2: single writer per b element.
__global__ void bias_final_kernel(const double* __restrict__ bpart,
                                  const float* __restrict__ bu,
                                  const float* __restrict__ bl,
                                  float* __restrict__ out) {
    int sb = blockIdx.x;         // 0..15
    int t  = threadIdx.x;        // 64, only t<32 active
    if (t >= NOUT) return;
    double s = 0.0;
    for (int h = 0; h < 32; h++) s += bpart[(size_t)(sb * 32 + h) * 32 + t];
    int side = sb >> 3, b = sb & 7;
    const float* bb = side ? bl : bu;
    out[(side ? BL_OFF : BU_OFF) + b * NOUT + t] =
        (float)((double)bb[b * NOUT + t] + s);
}

extern "C" void kernel_launch(void* const* d_in, const int* in_sizes, int n_in,
                              void* d_out, int out_size, void* d_ws, size_t ws_size,
                              hipStream_t stream) {
    const float* wu   = (const float*)d_in[0];
    const float* bu   = (const float*)d_in[1];
    const float* wl   = (const float*)d_in[2];
    const float* bl   = (const float*)d_in[3];
    const float* K    = (const float*)d_in[4];
    const float* bias = (const float*)d_in[5];
    float* out = (float*)d_out;
    unsigned int* kws = (unsigned int*)d_ws;
    double* bpart = (double*)((char*)d_ws + BP_OFF_BYTES);

    prep_kernel<<<dim3(9), dim3(256), 0, stream>>>(K, kws);
    conv_bwd_kernel<<<dim3(4096), dim3(256), 0, stream>>>(wu, wl, (const uint4*)d_ws, out);
    bias_part_kernel<<<dim3(512), dim3(256), 0, stream>>>(wu, wl, bias, bpart);
    bias_final_kernel<<<dim3(16), dim3(64), 0, stream>>>(bpart, bu, bl, out);
}